// Round 1
// baseline (23301.335 us; speedup 1.0000x reference)
//
#include <hip/hip_runtime.h>
#include <math.h>

namespace {
constexpr int S = 256;
constexpr int H = 768;
constexpr int NLAY = 12;
constexpr int NHD = 12;
constexpr int FF = 3072;
constexpr int LBL = 9;
constexpr int DH = 64;
constexpr int BATCH = 32;
constexpr int TOKENS = BATCH * S;      // 8192
constexpr float SCALE = 0.125f;        // 1/sqrt(64)

// workspace layout (floats)
constexpr size_t H_OFF   = 0;                       // h       [8192*768]
constexpr size_t Q_OFF   = H_OFF + (size_t)TOKENS*H;   // q / ctx / ff2out
constexpr size_t K_OFF   = Q_OFF + (size_t)TOKENS*H;   // k / attn-proj out
constexpr size_t V_OFF   = K_OFF + (size_t)TOKENS*H;   // v
constexpr size_t BIG_OFF = V_OFF + (size_t)TOKENS*H;   // att scores [B,NH,S,S] == ff1 [8192*3072]
constexpr size_t EM_OFF  = BIG_OFF + (size_t)TOKENS*FF;
constexpr size_t PART_OFF= EM_OFF + (size_t)TOKENS*LBL;
constexpr size_t WS_FLOATS = PART_OFF + 64;
}

__device__ inline float gelu_tanh(float x) {
    float x3 = x * x * x;
    return 0.5f * x * (1.0f + tanhf(0.7978845608028654f * (x + 0.044715f * x3)));
}

// ---------------- generic tiled f32 GEMM ----------------
// C[m,n] = act( sum_k A[m,k]*B[k,n] + bias[n] )
// TRANSB: B element [k][n] read from B[n*ldb + k]  (i.e. B given row-major [N,K])
// batch z: outer = z/innerN, inner = z%innerN; ptr += outer*s?b + inner*s?h
template<int BM, int BN, int BK, int TM, int TN, bool TRANSB>
__global__ __launch_bounds__(256) void gemm_f32(
    const float* __restrict__ A, int lda, long long sAb, long long sAh,
    const float* __restrict__ B, int ldb, long long sBb, long long sBh,
    const float* __restrict__ bias,
    float* __restrict__ C, int ldc, long long sCb, long long sCh,
    int K, int act, int innerN)
{
    __shared__ __align__(16) float As[BK][BM];
    __shared__ __align__(16) float Bs[BK][BN];
    const int tid = threadIdx.x;
    const int bm = blockIdx.y * BM, bn = blockIdx.x * BN;
    const int ob = blockIdx.z / innerN, ih = blockIdx.z % innerN;
    const float* Ab = A + ob * sAb + ih * sAh;
    const float* Bb = B + ob * sBb + ih * sBh;
    float* Cb = C + ob * sCb + ih * sCh;

    const int tn = (tid % (BN / TN)) * TN;
    const int tm = (tid / (BN / TN)) * TM;

    float acc[TM][TN];
#pragma unroll
    for (int i = 0; i < TM; ++i)
#pragma unroll
        for (int j = 0; j < TN; ++j) acc[i][j] = 0.f;

    for (int k0 = 0; k0 < K; k0 += BK) {
        // load A tile (BM x BK), store transposed As[k][m]
        for (int i = tid; i < BM * BK / 4; i += 256) {
            int row = i / (BK / 4);
            int k4 = (i % (BK / 4)) * 4;
            const float4 v = *(const float4*)(Ab + (size_t)(bm + row) * lda + k0 + k4);
            As[k4 + 0][row] = v.x; As[k4 + 1][row] = v.y;
            As[k4 + 2][row] = v.z; As[k4 + 3][row] = v.w;
        }
        // load B tile (BK x BN)
        if (!TRANSB) {
            for (int i = tid; i < BK * BN / 4; i += 256) {
                int row = i / (BN / 4);
                int c4 = (i % (BN / 4)) * 4;
                *(float4*)&Bs[row][c4] =
                    *(const float4*)(Bb + (size_t)(k0 + row) * ldb + bn + c4);
            }
        } else {
            for (int i = tid; i < BK * BN / 4; i += 256) {
                int col = i / (BK / 4);
                int k4 = (i % (BK / 4)) * 4;
                const float4 v = *(const float4*)(Bb + (size_t)(bn + col) * ldb + k0 + k4);
                Bs[k4 + 0][col] = v.x; Bs[k4 + 1][col] = v.y;
                Bs[k4 + 2][col] = v.z; Bs[k4 + 3][col] = v.w;
            }
        }
        __syncthreads();
#pragma unroll
        for (int kk = 0; kk < BK; ++kk) {
            float ar[TM], br[TN];
#pragma unroll
            for (int i = 0; i < TM; i += 4) *(float4*)&ar[i] = *(const float4*)&As[kk][tm + i];
#pragma unroll
            for (int j = 0; j < TN; j += 4) *(float4*)&br[j] = *(const float4*)&Bs[kk][tn + j];
#pragma unroll
            for (int i = 0; i < TM; ++i)
#pragma unroll
                for (int j = 0; j < TN; ++j) acc[i][j] = fmaf(ar[i], br[j], acc[i][j]);
        }
        __syncthreads();
    }
    // epilogue
#pragma unroll
    for (int i = 0; i < TM; ++i) {
#pragma unroll
        for (int j = 0; j < TN; j += 4) {
            float4 v;
            float* pv = (float*)&v;
#pragma unroll
            for (int q = 0; q < 4; ++q) {
                float x = acc[i][j + q];
                if (bias) x += bias[bn + tn + j + q];
                if (act == 1) x = gelu_tanh(x);
                pv[q] = x;
            }
            *(float4*)(Cb + (size_t)(bm + tm + i) * ldc + bn + tn + j) = v;
        }
    }
}

// ---------------- block reduce helper (sum of two values) ----------------
__device__ inline void blk_reduce2(float& s, float& ss, float* red) {
#pragma unroll
    for (int m = 32; m; m >>= 1) { s += __shfl_xor(s, m); ss += __shfl_xor(ss, m); }
    int w = threadIdx.x >> 6;
    if ((threadIdx.x & 63) == 0) { red[w] = s; red[4 + w] = ss; }
    __syncthreads();
    s = red[0] + red[1] + red[2] + red[3];
    ss = red[4] + red[5] + red[6] + red[7];
}

// ---------------- embeddings + LN ----------------
__global__ __launch_bounds__(256) void embed_ln_k(
    const int* __restrict__ ids, const int* __restrict__ tts,
    const float* __restrict__ wemb, const float* __restrict__ pemb,
    const float* __restrict__ temb, const float* __restrict__ g,
    const float* __restrict__ bp, float* __restrict__ h)
{
    int tok = blockIdx.x, tid = threadIdx.x;
    int spos = tok & (S - 1);
    int id = ids[tok], tt = tts[tok];
    const float* wr = wemb + (size_t)id * H;
    const float* pr = pemb + (size_t)spos * H;
    const float* tr = temb + (size_t)tt * H;
    float x[3]; float s = 0.f, ss = 0.f;
#pragma unroll
    for (int j = 0; j < 3; ++j) {
        int d = tid + 256 * j;
        x[j] = wr[d] + pr[d] + tr[d];
        s += x[j]; ss += x[j] * x[j];
    }
    __shared__ float red[8];
    blk_reduce2(s, ss, red);
    float mu = s * (1.f / H);
    float var = ss * (1.f / H) - mu * mu;
    float rs = rsqrtf(var + 1e-12f);
#pragma unroll
    for (int j = 0; j < 3; ++j) {
        int d = tid + 256 * j;
        h[(size_t)tok * H + d] = (x[j] - mu) * rs * g[d] + bp[d];
    }
}

// ---------------- residual add + LN (in place on h) ----------------
__global__ __launch_bounds__(256) void add_ln_k(
    float* __restrict__ h, const float* __restrict__ add,
    const float* __restrict__ g, const float* __restrict__ bp)
{
    int tok = blockIdx.x, tid = threadIdx.x;
    float x[3]; float s = 0.f, ss = 0.f;
#pragma unroll
    for (int j = 0; j < 3; ++j) {
        int d = tid + 256 * j;
        x[j] = h[(size_t)tok * H + d] + add[(size_t)tok * H + d];
        s += x[j]; ss += x[j] * x[j];
    }
    __shared__ float red[8];
    blk_reduce2(s, ss, red);
    float mu = s * (1.f / H);
    float var = ss * (1.f / H) - mu * mu;
    float rs = rsqrtf(var + 1e-12f);
#pragma unroll
    for (int j = 0; j < 3; ++j) {
        int d = tid + 256 * j;
        h[(size_t)tok * H + d] = (x[j] - mu) * rs * g[d] + bp[d];
    }
}

// ---------------- scale + mask bias + row softmax on att scores ----------------
// grid: B*NH*(S/16) blocks; block 256; 16 rows per block, 16 lanes per row
__global__ __launch_bounds__(256) void attn_softmax_k(
    float* __restrict__ att, const int* __restrict__ mask)
{
    int blk = blockIdx.x, tid = threadIdx.x;
    int bh = blk >> 4;              // b*NH + h
    int r0 = (blk & 15) * 16;
    int b = bh / NHD;
    float* base = att + ((size_t)bh * S + r0) * S;
    const int* mrow = mask + (size_t)b * S;
    __shared__ float sc[16][S + 1];
    for (int i = tid; i < 16 * S; i += 256) {
        int r = i >> 8, c = i & (S - 1);
        sc[r][c] = base[(size_t)r * S + c] * SCALE + (mrow[c] ? 0.f : -1e9f);
    }
    __syncthreads();
    int r = tid >> 4, c0 = tid & 15;
    float mx = -1e30f;
#pragma unroll
    for (int i = 0; i < 16; ++i) mx = fmaxf(mx, sc[r][c0 + 16 * i]);
#pragma unroll
    for (int m = 8; m; m >>= 1) mx = fmaxf(mx, __shfl_xor(mx, m));
    float sum = 0.f;
#pragma unroll
    for (int i = 0; i < 16; ++i) sum += expf(sc[r][c0 + 16 * i] - mx);
#pragma unroll
    for (int m = 8; m; m >>= 1) sum += __shfl_xor(sum, m);
    float inv = 1.f / sum;
#pragma unroll
    for (int i = 0; i < 16; ++i) {
        int c = c0 + 16 * i;
        sc[r][c] = expf(sc[r][c] - mx) * inv;
    }
    __syncthreads();
    for (int i = tid; i < 16 * S; i += 256) {
        int rr = i >> 8, c = i & (S - 1);
        base[(size_t)rr * S + c] = sc[rr][c];
    }
}

// ---------------- logits + log_softmax over 9 labels ----------------
__global__ __launch_bounds__(256) void logits_k(
    const float* __restrict__ h, const float* __restrict__ fcw, float* __restrict__ em)
{
    int tok = blockIdx.x, tid = threadIdx.x;
    float p[LBL];
#pragma unroll
    for (int l = 0; l < LBL; ++l) p[l] = 0.f;
    const float* hr = h + (size_t)tok * H;
#pragma unroll
    for (int j = 0; j < 3; ++j) {
        int d = tid + 256 * j;
        float hv = hr[d];
        const float* fr = fcw + (size_t)d * LBL;
#pragma unroll
        for (int l = 0; l < LBL; ++l) p[l] = fmaf(hv, fr[l], p[l]);
    }
    __shared__ float ls[4][LBL];
    __shared__ float lg[LBL];
    __shared__ float lse;
#pragma unroll
    for (int l = 0; l < LBL; ++l) {
        float v = p[l];
#pragma unroll
        for (int m = 32; m; m >>= 1) v += __shfl_xor(v, m);
        if ((tid & 63) == 0) ls[tid >> 6][l] = v;
    }
    __syncthreads();
    if (tid < LBL) lg[tid] = ls[0][tid] + ls[1][tid] + ls[2][tid] + ls[3][tid];
    __syncthreads();
    if (tid == 0) {
        float mx = lg[0];
#pragma unroll
        for (int j = 1; j < LBL; ++j) mx = fmaxf(mx, lg[j]);
        float sm = 0.f;
#pragma unroll
        for (int j = 0; j < LBL; ++j) sm += expf(lg[j] - mx);
        lse = mx + logf(sm);
    }
    __syncthreads();
    if (tid < LBL) em[(size_t)tok * LBL + tid] = lg[tid] - lse;
}

// ---------------- CRF: per-batch (den - num), one wave per b ----------------
__global__ __launch_bounds__(64) void crf_k(
    const float* __restrict__ em, const int* __restrict__ tags,
    const int* __restrict__ mask, const float* __restrict__ sp,
    const float* __restrict__ ep, const float* __restrict__ trans,
    float* __restrict__ partial)
{
    int b = blockIdx.x, t = threadIdx.x;
    __shared__ float tr[LBL * LBL];
    __shared__ float alpha[LBL];
    for (int i = t; i < LBL * LBL; i += 64) tr[i] = trans[i];
    const float* emb = em + (size_t)b * S * LBL;
    const int* tg = tags + (size_t)b * S;
    const int* mk = mask + (size_t)b * S;

    int cnt = 0; float ns = 0.f;
    for (int i = t; i < S; i += 64) {
        int m = mk[i];
        cnt += (m != 0);
        if (i >= 1 && m)
            ns += trans[tg[i - 1] * LBL + tg[i]] + emb[(size_t)i * LBL + tg[i]];
    }
#pragma unroll
    for (int m = 32; m; m >>= 1) { cnt += __shfl_xor(cnt, m); ns += __shfl_xor(ns, m); }
    float num = ns + sp[tg[0]] + emb[tg[0]] + ep[tg[cnt - 1]];

    if (t < LBL) alpha[t] = sp[t] + emb[t];
    __syncthreads();
    for (int step = 1; step < S; ++step) {
        float na = 0.f;
        if (t < LBL) {
            if (mk[step]) {
                float mx = -1e30f;
#pragma unroll
                for (int i = 0; i < LBL; ++i) mx = fmaxf(mx, alpha[i] + tr[i * LBL + t]);
                float sm = 0.f;
#pragma unroll
                for (int i = 0; i < LBL; ++i) sm += expf(alpha[i] + tr[i * LBL + t] - mx);
                na = mx + logf(sm) + emb[(size_t)step * LBL + t];
            } else {
                na = alpha[t];
            }
        }
        __syncthreads();
        if (t < LBL) alpha[t] = na;
        __syncthreads();
    }
    if (t == 0) {
        float mx = -1e30f;
#pragma unroll
        for (int j = 0; j < LBL; ++j) mx = fmaxf(mx, alpha[j] + ep[j]);
        float sm = 0.f;
#pragma unroll
        for (int j = 0; j < LBL; ++j) sm += expf(alpha[j] + ep[j] - mx);
        partial[b] = (mx + logf(sm)) - num;
    }
}

__global__ void finalize_k(const float* __restrict__ partial, float* __restrict__ out) {
    float s = 0.f;
    for (int i = 0; i < BATCH; ++i) s += partial[i];
    out[0] = s;
}

__global__ void sentinel_k(float* out) { out[0] = -12345.0f; }

extern "C" void kernel_launch(void* const* d_in, const int* in_sizes, int n_in,
                              void* d_out, int out_size, void* d_ws, size_t ws_size,
                              hipStream_t stream) {
    (void)in_sizes; (void)n_in; (void)out_size;
    const int* token_ids  = (const int*)d_in[0];
    const int* token_type = (const int*)d_in[1];
    const int* amask      = (const int*)d_in[2];
    const int* y          = (const int*)d_in[3];
    const float* wemb = (const float*)d_in[4];
    const float* pemb = (const float*)d_in[5];
    const float* temb = (const float*)d_in[6];
    const float* eg   = (const float*)d_in[7];
    const float* eb   = (const float*)d_in[8];
    const float* Wq = (const float*)d_in[9];
    const float* bq = (const float*)d_in[10];
    const float* Wk = (const float*)d_in[11];
    const float* bk = (const float*)d_in[12];
    const float* Wv = (const float*)d_in[13];
    const float* bv = (const float*)d_in[14];
    const float* Wo = (const float*)d_in[15];
    const float* bo = (const float*)d_in[16];
    const float* ln1g = (const float*)d_in[17];
    const float* ln1b = (const float*)d_in[18];
    const float* W1 = (const float*)d_in[19];
    const float* b1 = (const float*)d_in[20];
    const float* W2 = (const float*)d_in[21];
    const float* b2 = (const float*)d_in[22];
    const float* ln2g = (const float*)d_in[23];
    const float* ln2b = (const float*)d_in[24];
    const float* fcw = (const float*)d_in[25];
    const float* crf_s = (const float*)d_in[26];
    const float* crf_e = (const float*)d_in[27];
    const float* crf_t = (const float*)d_in[28];

    if (ws_size < WS_FLOATS * sizeof(float)) {
        sentinel_k<<<1, 1, 0, stream>>>((float*)d_out);
        return;
    }

    float* ws = (float*)d_ws;
    float* hbuf = ws + H_OFF;
    float* qbuf = ws + Q_OFF;
    float* kbuf = ws + K_OFF;
    float* vbuf = ws + V_OFF;
    float* big  = ws + BIG_OFF;   // att scores [B,NH,S,S], then ff1 [8192,3072]
    float* embuf = ws + EM_OFF;
    float* part  = ws + PART_OFF;

    // 1. embeddings + LN
    embed_ln_k<<<TOKENS, 256, 0, stream>>>(token_ids, token_type, wemb, pemb, temb,
                                           eg, eb, hbuf);

    constexpr long long HH = (long long)H * H;       // 589824
    constexpr long long HF = (long long)H * FF;      // 2359296
    constexpr long long TOKH = (long long)S * H;     // per-batch stride in q/k/v (196608)
    constexpr long long ATT_B = (long long)NHD * S * S;  // 786432
    constexpr long long ATT_H = (long long)S * S;        // 65536

    dim3 gProj(H / 128, TOKENS / 128, 1);     // 6 x 64
    dim3 gFF1(FF / 128, TOKENS / 128, 1);     // 24 x 64
    dim3 gScores(S / 64, S / 64, BATCH * NHD);  // 4 x 4 x 384
    dim3 gAttV(DH / 64, S / 64, BATCH * NHD);   // 1 x 4 x 384

    for (int l = 0; l < NLAY; ++l) {
        const float* Wq_l = Wq + l * HH; const float* bq_l = bq + l * H;
        const float* Wk_l = Wk + l * HH; const float* bk_l = bk + l * H;
        const float* Wv_l = Wv + l * HH; const float* bv_l = bv + l * H;
        const float* Wo_l = Wo + l * HH; const float* bo_l = bo + l * H;
        const float* W1_l = W1 + l * HF; const float* b1_l = b1 + (long long)l * FF;
        const float* W2_l = W2 + l * HF; const float* b2_l = b2 + l * H;

        // q, k, v projections
        gemm_f32<128,128,16,8,8,false><<<gProj, 256, 0, stream>>>(
            hbuf, H, 0, 0, Wq_l, H, 0, 0, bq_l, qbuf, H, 0, 0, H, 0, 1);
        gemm_f32<128,128,16,8,8,false><<<gProj, 256, 0, stream>>>(
            hbuf, H, 0, 0, Wk_l, H, 0, 0, bk_l, kbuf, H, 0, 0, H, 0, 1);
        gemm_f32<128,128,16,8,8,false><<<gProj, 256, 0, stream>>>(
            hbuf, H, 0, 0, Wv_l, H, 0, 0, bv_l, vbuf, H, 0, 0, H, 0, 1);

        // scores = q @ k^T  (per b,h): M=S, N=S, K=DH
        gemm_f32<64,64,16,4,4,true><<<gScores, 256, 0, stream>>>(
            qbuf, H, TOKH, DH, kbuf, H, TOKH, DH, nullptr,
            big, S, ATT_B, ATT_H, DH, 0, NHD);

        // scale + mask + softmax
        attn_softmax_k<<<BATCH * NHD * (S / 16), 256, 0, stream>>>(big, amask);

        // ctx = att @ v : M=S, N=DH, K=S  -> qbuf (as [B,S,NH,DH])
        gemm_f32<64,64,16,4,4,false><<<gAttV, 256, 0, stream>>>(
            big, S, ATT_B, ATT_H, vbuf, H, TOKH, DH, nullptr,
            qbuf, H, TOKH, DH, S, 0, NHD);

        // attention output projection -> kbuf
        gemm_f32<128,128,16,8,8,false><<<gProj, 256, 0, stream>>>(
            qbuf, H, 0, 0, Wo_l, H, 0, 0, bo_l, kbuf, H, 0, 0, H, 0, 1);

        // h = LN(h + kbuf)
        add_ln_k<<<TOKENS, 256, 0, stream>>>(hbuf, kbuf, ln1g + l * H, ln1b + l * H);

        // ff1 = gelu(h @ W1 + b1) -> big
        gemm_f32<128,128,16,8,8,false><<<gFF1, 256, 0, stream>>>(
            hbuf, H, 0, 0, W1_l, FF, 0, 0, b1_l, big, FF, 0, 0, H, 1, 1);

        // ff2 = big @ W2 + b2 -> qbuf
        gemm_f32<128,128,16,8,8,false><<<gProj, 256, 0, stream>>>(
            big, FF, 0, 0, W2_l, H, 0, 0, b2_l, qbuf, H, 0, 0, FF, 0, 1);

        // h = LN(h + qbuf)
        add_ln_k<<<TOKENS, 256, 0, stream>>>(hbuf, qbuf, ln2g + l * H, ln2b + l * H);
    }

    // logits + log_softmax
    logits_k<<<TOKENS, 256, 0, stream>>>(hbuf, fcw, embuf);

    // CRF per-batch, then deterministic reduce
    crf_k<<<BATCH, 64, 0, stream>>>(embuf, y, amask, crf_s, crf_e, crf_t, part);
    finalize_k<<<1, 1, 0, stream>>>(part, (float*)d_out);
}

// Round 2
// 4237.663 us; speedup vs baseline: 5.4986x; 5.4986x over previous
//
#include <hip/hip_runtime.h>
#include <math.h>

typedef unsigned short ushortT;
typedef __attribute__((ext_vector_type(4))) float f32x4;
typedef __attribute__((ext_vector_type(4))) unsigned int u32x4;
typedef __attribute__((ext_vector_type(4))) unsigned short u16x4;

namespace {
constexpr int S = 256;
constexpr int H = 768;
constexpr int NLAY = 12;
constexpr int NHD = 12;
constexpr int FF = 3072;
constexpr int LBL = 9;
constexpr int DH = 64;
constexpr int BATCH = 32;
constexpr int TOKENS = BATCH * S;      // 8192
constexpr float SCALE = 0.125f;        // 1/sqrt(64)

// workspace layout (float-slot units)
constexpr size_t H_OFF   = 0;                          // h f32 [8192*768]
constexpr size_t TMP_OFF = H_OFF  + (size_t)TOKENS*H;  // residual-add input f32
constexpr size_t HB_OFF  = TMP_OFF+ (size_t)TOKENS*H;  // h bf16 (half slots)
constexpr size_t QB_OFF  = HB_OFF + (size_t)TOKENS*H/2;  // q / ctx bf16
constexpr size_t KB_OFF  = QB_OFF + (size_t)TOKENS*H/2;  // k bf16
constexpr size_t VT_OFF  = KB_OFF + (size_t)TOKENS*H/2;  // v^T bf16 [B*NH*DH][S]
constexpr size_t BIG_OFF = VT_OFF + (size_t)TOKENS*H/2;  // scores bf16 [B,NH,S,S] == ff1 bf16 [8192,3072]
constexpr size_t WTQ_OFF = BIG_OFF + (size_t)TOKENS*FF/2;
constexpr size_t WTK_OFF = WTQ_OFF + (size_t)H*H/2;
constexpr size_t WTV_OFF = WTK_OFF + (size_t)H*H/2;
constexpr size_t WTO_OFF = WTV_OFF + (size_t)H*H/2;
constexpr size_t WT1_OFF = WTO_OFF + (size_t)H*H/2;      // W1^T [3072][768]
constexpr size_t WT2_OFF = WT1_OFF + (size_t)H*FF/2;     // W2^T [768][3072]
constexpr size_t EM_OFF  = WT2_OFF + (size_t)H*FF/2;
constexpr size_t PART_OFF= EM_OFF + (size_t)TOKENS*LBL;
constexpr size_t WS_FLOATS = PART_OFF + 64;
}

__device__ __forceinline__ ushortT f2bf(float x) {
    unsigned u = __builtin_bit_cast(unsigned, x);
    u += 0x7fffu + ((u >> 16) & 1u);
    return (ushortT)(u >> 16);
}
__device__ __forceinline__ float bf2f(ushortT h) {
    unsigned u = ((unsigned)h) << 16;
    return __builtin_bit_cast(float, u);
}

__device__ inline float gelu_tanh(float x) {
    float x3 = x * x * x;
    return 0.5f * x * (1.0f + tanhf(0.7978845608028654f * (x + 0.044715f * x3)));
}

__device__ __forceinline__ void mfma_bf16(f32x4& c, const u32x4& a, const u32x4& b) {
    asm("v_mfma_f32_16x16x32_bf16 %0, %1, %2, %0" : "+v"(c) : "v"(a), "v"(b));
}

__device__ __forceinline__ void gload_lds16(const ushortT* g, ushortT* l) {
    __builtin_amdgcn_global_load_lds(
        (const __attribute__((address_space(1))) unsigned int*)g,
        (__attribute__((address_space(3))) unsigned int*)l,
        16, 0, 0);
}

// ---------------- bf16 MFMA GEMM ----------------
// C[m,n] = epilogue( sum_k A[m,k] * Bt[n,k] + bias[n] )
// Tile: BM=WM*64 x BN=WN*64, BK=32, 4 waves of 64x64 each.
// MODE: 0 = bf16 out + bias, 1 = bf16 + bias + gelu, 2 = f32 out + bias,
//       3 = bf16 + bias, V^T-per-head write (Cv = vt base), 4 = bf16, no bias
template<int WM, int WN, int MODE>
__global__ __launch_bounds__(256) void gemm_mfma(
    const ushortT* __restrict__ A, int lda, long long sAo, long long sAi,
    const ushortT* __restrict__ Bt, int ldb, long long sBo, long long sBi,
    const float* __restrict__ bias,
    void* __restrict__ Cv, int ldc, long long sCo, long long sCi,
    int K, int innerN)
{
    constexpr int BM = WM * 64, BN = WN * 64;
    __shared__ __align__(16) ushortT As[BM * 32];
    __shared__ __align__(16) ushortT Bs[BN * 32];
    const int tid = threadIdx.x;
    const int wave = tid >> 6, lane = tid & 63;
    const int ob = blockIdx.z / innerN, ib = blockIdx.z - ob * innerN;
    const int bm = blockIdx.y * BM, bn = blockIdx.x * BN;
    const ushortT* Ab = A + ob * sAo + ib * sAi + (size_t)bm * lda;
    const ushortT* Bb = Bt + ob * sBo + ib * sBi + (size_t)bn * ldb;
    const int wm = wave / WN, wn = wave - wm * WN;

    const int lrow = lane >> 2;          // 0..15 within 1KB chunk
    const int lk16 = (lane & 3) * 8;     // element offset (8 bf16 = 16B)
    const int rl = lane & 15;
    const int kg = (lane >> 4) * 8;

    f32x4 acc[4][4];
#pragma unroll
    for (int i = 0; i < 4; ++i)
#pragma unroll
        for (int j = 0; j < 4; ++j) acc[i][j] = (f32x4){0.f, 0.f, 0.f, 0.f};

    for (int k0 = 0; k0 < K; k0 += 32) {
        if (k0) __syncthreads();
#pragma unroll
        for (int j = 0; j < WM; ++j) {
            int chunk = j * 4 + wave;
            gload_lds16(Ab + (size_t)(chunk * 16 + lrow) * lda + k0 + lk16,
                        As + chunk * 512);
        }
#pragma unroll
        for (int j = 0; j < WN; ++j) {
            int chunk = j * 4 + wave;
            gload_lds16(Bb + (size_t)(chunk * 16 + lrow) * ldb + k0 + lk16,
                        Bs + chunk * 512);
        }
        __syncthreads();

        u32x4 a[4], b[4];
#pragma unroll
        for (int mf = 0; mf < 4; ++mf)
            a[mf] = *(const u32x4*)(As + (wm * 64 + mf * 16 + rl) * 32 + kg);
#pragma unroll
        for (int nf = 0; nf < 4; ++nf)
            b[nf] = *(const u32x4*)(Bs + (wn * 64 + nf * 16 + rl) * 32 + kg);
#pragma unroll
        for (int mf = 0; mf < 4; ++mf)
#pragma unroll
            for (int nf = 0; nf < 4; ++nf)
                mfma_bf16(acc[mf][nf], a[mf], b[nf]);
    }

    // epilogue
    float* Cf = (float*)Cv + ob * sCo + ib * sCi;
    ushortT* Ch = (ushortT*)Cv + ob * sCo + ib * sCi;
#pragma unroll
    for (int nf = 0; nf < 4; ++nf) {
        int gn = bn + wn * 64 + nf * 16 + rl;
        float bv = 0.f;
        if constexpr (MODE != 4) bv = bias[gn];
#pragma unroll
        for (int mf = 0; mf < 4; ++mf) {
            int gm = bm + wm * 64 + mf * 16 + ((lane >> 4) << 2);
            if constexpr (MODE == 3) {
                u16x4 o;
#pragma unroll
                for (int r = 0; r < 4; ++r) o[r] = f2bf(acc[mf][nf][r] + bv);
                int b_ = gm >> 8, s0 = gm & 255;
                int h_ = gn >> 6, dh = gn & 63;
                *(u16x4*)((ushortT*)Cv +
                          (((size_t)(b_ * NHD + h_) * DH + dh) << 8) + s0) = o;
            } else if constexpr (MODE == 2) {
#pragma unroll
                for (int r = 0; r < 4; ++r)
                    Cf[(size_t)(gm + r) * ldc + gn] = acc[mf][nf][r] + bv;
            } else {
#pragma unroll
                for (int r = 0; r < 4; ++r) {
                    float x = acc[mf][nf][r] + bv;
                    if constexpr (MODE == 1) x = gelu_tanh(x);
                    Ch[(size_t)(gm + r) * ldc + gn] = f2bf(x);
                }
            }
        }
    }
}

// ---------------- f32 [R][C] -> bf16 [C][R] transpose+cast ----------------
__global__ __launch_bounds__(256) void transpose_cast_k(
    const float* __restrict__ W, ushortT* __restrict__ WT, int R, int C)
{
    __shared__ float t[32][33];
    int r0 = blockIdx.y * 32, c0 = blockIdx.x * 32;
    int tr = threadIdx.x >> 3;
    int tc4 = (threadIdx.x & 7) * 4;
    const float4 v = *(const float4*)(W + (size_t)(r0 + tr) * C + c0 + tc4);
    t[tr][tc4 + 0] = v.x; t[tr][tc4 + 1] = v.y;
    t[tr][tc4 + 2] = v.z; t[tr][tc4 + 3] = v.w;
    __syncthreads();
    u16x4 o;
#pragma unroll
    for (int q = 0; q < 4; ++q) o[q] = f2bf(t[tc4 + q][tr]);
    *(u16x4*)(WT + (size_t)(c0 + tr) * R + r0 + tc4) = o;
}

// ---------------- block reduce helper ----------------
__device__ inline void blk_reduce2(float& s, float& ss, float* red) {
#pragma unroll
    for (int m = 32; m; m >>= 1) { s += __shfl_xor(s, m); ss += __shfl_xor(ss, m); }
    int w = threadIdx.x >> 6;
    if ((threadIdx.x & 63) == 0) { red[w] = s; red[4 + w] = ss; }
    __syncthreads();
    s = red[0] + red[1] + red[2] + red[3];
    ss = red[4] + red[5] + red[6] + red[7];
}

// ---------------- embeddings + LN (emit f32 + bf16) ----------------
__global__ __launch_bounds__(256) void embed_ln_k(
    const int* __restrict__ ids, const int* __restrict__ tts,
    const float* __restrict__ wemb, const float* __restrict__ pemb,
    const float* __restrict__ temb, const float* __restrict__ g,
    const float* __restrict__ bp, float* __restrict__ h, ushortT* __restrict__ hb)
{
    int tok = blockIdx.x, tid = threadIdx.x;
    int spos = tok & (S - 1);
    int id = ids[tok], tt = tts[tok];
    const float* wr = wemb + (size_t)id * H;
    const float* pr = pemb + (size_t)spos * H;
    const float* tr = temb + (size_t)tt * H;
    float x[3]; float s = 0.f, ss = 0.f;
#pragma unroll
    for (int j = 0; j < 3; ++j) {
        int d = tid + 256 * j;
        x[j] = wr[d] + pr[d] + tr[d];
        s += x[j]; ss += x[j] * x[j];
    }
    __shared__ float red[8];
    blk_reduce2(s, ss, red);
    float mu = s * (1.f / H);
    float var = ss * (1.f / H) - mu * mu;
    float rs = rsqrtf(var + 1e-12f);
#pragma unroll
    for (int j = 0; j < 3; ++j) {
        int d = tid + 256 * j;
        float y = (x[j] - mu) * rs * g[d] + bp[d];
        h[(size_t)tok * H + d] = y;
        hb[(size_t)tok * H + d] = f2bf(y);
    }
}

// ---------------- residual add + LN (in place on h, emit bf16) ----------------
__global__ __launch_bounds__(256) void add_ln_k(
    float* __restrict__ h, const float* __restrict__ add,
    const float* __restrict__ g, const float* __restrict__ bp,
    ushortT* __restrict__ hb)
{
    int tok = blockIdx.x, tid = threadIdx.x;
    float x[3]; float s = 0.f, ss = 0.f;
#pragma unroll
    for (int j = 0; j < 3; ++j) {
        int d = tid + 256 * j;
        x[j] = h[(size_t)tok * H + d] + add[(size_t)tok * H + d];
        s += x[j]; ss += x[j] * x[j];
    }
    __shared__ float red[8];
    blk_reduce2(s, ss, red);
    float mu = s * (1.f / H);
    float var = ss * (1.f / H) - mu * mu;
    float rs = rsqrtf(var + 1e-12f);
#pragma unroll
    for (int j = 0; j < 3; ++j) {
        int d = tid + 256 * j;
        float y = (x[j] - mu) * rs * g[d] + bp[d];
        h[(size_t)tok * H + d] = y;
        hb[(size_t)tok * H + d] = f2bf(y);
    }
}

// ---------------- scale + mask + softmax on bf16 scores (in place) ----------------
// grid: B*NH*(S/16); 16 rows/block, 16 lanes per row, 16 elems per lane, no LDS
__global__ __launch_bounds__(256) void attn_softmax_bf16_k(
    ushortT* __restrict__ att, const int* __restrict__ mask)
{
    int blk = blockIdx.x, tid = threadIdx.x;
    int bh = blk >> 4;
    int r0 = (blk & 15) * 16;
    int b = bh / NHD;
    int r = tid >> 4, c0 = (tid & 15) * 16;
    ushortT* rp = att + ((size_t)bh * S + r0 + r) * S;
    const int* mrow = mask + (size_t)b * S;

    u32x4 x0 = *(const u32x4*)(rp + c0);
    u32x4 x1 = *(const u32x4*)(rp + c0 + 8);
    unsigned w[8];
    *(u32x4*)&w[0] = x0; *(u32x4*)&w[4] = x1;
    float v[16];
#pragma unroll
    for (int i = 0; i < 8; ++i) {
        v[2 * i]     = bf2f((ushortT)(w[i] & 0xffffu));
        v[2 * i + 1] = bf2f((ushortT)(w[i] >> 16));
    }
#pragma unroll
    for (int j = 0; j < 16; ++j)
        v[j] = v[j] * SCALE + (mrow[c0 + j] ? 0.f : -1e9f);
    float mx = -1e30f;
#pragma unroll
    for (int j = 0; j < 16; ++j) mx = fmaxf(mx, v[j]);
#pragma unroll
    for (int m = 8; m; m >>= 1) mx = fmaxf(mx, __shfl_xor(mx, m));
    float sum = 0.f;
#pragma unroll
    for (int j = 0; j < 16; ++j) { v[j] = expf(v[j] - mx); sum += v[j]; }
#pragma unroll
    for (int m = 8; m; m >>= 1) sum += __shfl_xor(sum, m);
    float inv = 1.f / sum;
#pragma unroll
    for (int i = 0; i < 8; ++i)
        w[i] = (unsigned)f2bf(v[2 * i] * inv) |
               ((unsigned)f2bf(v[2 * i + 1] * inv) << 16);
    *(u32x4*)(rp + c0) = *(u32x4*)&w[0];
    *(u32x4*)(rp + c0 + 8) = *(u32x4*)&w[4];
}

// ---------------- logits + log_softmax over 9 labels (f32 exact) ----------------
__global__ __launch_bounds__(256) void logits_k(
    const float* __restrict__ h, const float* __restrict__ fcw, float* __restrict__ em)
{
    int tok = blockIdx.x, tid = threadIdx.x;
    float p[LBL];
#pragma unroll
    for (int l = 0; l < LBL; ++l) p[l] = 0.f;
    const float* hr = h + (size_t)tok * H;
#pragma unroll
    for (int j = 0; j < 3; ++j) {
        int d = tid + 256 * j;
        float hv = hr[d];
        const float* fr = fcw + (size_t)d * LBL;
#pragma unroll
        for (int l = 0; l < LBL; ++l) p[l] = fmaf(hv, fr[l], p[l]);
    }
    __shared__ float ls[4][LBL];
    __shared__ float lg[LBL];
    __shared__ float lse;
#pragma unroll
    for (int l = 0; l < LBL; ++l) {
        float v = p[l];
#pragma unroll
        for (int m = 32; m; m >>= 1) v += __shfl_xor(v, m);
        if ((tid & 63) == 0) ls[tid >> 6][l] = v;
    }
    __syncthreads();
    if (tid < LBL) lg[tid] = ls[0][tid] + ls[1][tid] + ls[2][tid] + ls[3][tid];
    __syncthreads();
    if (tid == 0) {
        float mx = lg[0];
#pragma unroll
        for (int j = 1; j < LBL; ++j) mx = fmaxf(mx, lg[j]);
        float sm = 0.f;
#pragma unroll
        for (int j = 0; j < LBL; ++j) sm += expf(lg[j] - mx);
        lse = mx + logf(sm);
    }
    __syncthreads();
    if (tid < LBL) em[(size_t)tok * LBL + tid] = lg[tid] - lse;
}

// ---------------- CRF: per-batch (den - num), one wave per b ----------------
__global__ __launch_bounds__(64) void crf_k(
    const float* __restrict__ em, const int* __restrict__ tags,
    const int* __restrict__ mask, const float* __restrict__ sp,
    const float* __restrict__ ep, const float* __restrict__ trans,
    float* __restrict__ partial)
{
    int b = blockIdx.x, t = threadIdx.x;
    __shared__ float tr[LBL * LBL];
    __shared__ float alpha[LBL];
    for (int i = t; i < LBL * LBL; i += 64) tr[i] = trans[i];
    const float* emb = em + (size_t)b * S * LBL;
    const int* tg = tags + (size_t)b * S;
    const int* mk = mask + (size_t)b * S;

    int cnt = 0; float ns = 0.f;
    for (int i = t; i < S; i += 64) {
        int m = mk[i];
        cnt += (m != 0);
        if (i >= 1 && m)
            ns += trans[tg[i - 1] * LBL + tg[i]] + emb[(size_t)i * LBL + tg[i]];
    }
#pragma unroll
    for (int m = 32; m; m >>= 1) { cnt += __shfl_xor(cnt, m); ns += __shfl_xor(ns, m); }
    float num = ns + sp[tg[0]] + emb[tg[0]] + ep[tg[cnt - 1]];

    if (t < LBL) alpha[t] = sp[t] + emb[t];
    __syncthreads();
    for (int step = 1; step < S; ++step) {
        float na = 0.f;
        if (t < LBL) {
            if (mk[step]) {
                float mx = -1e30f;
#pragma unroll
                for (int i = 0; i < LBL; ++i) mx = fmaxf(mx, alpha[i] + tr[i * LBL + t]);
                float sm = 0.f;
#pragma unroll
                for (int i = 0; i < LBL; ++i) sm += expf(alpha[i] + tr[i * LBL + t] - mx);
                na = mx + logf(sm) + emb[(size_t)step * LBL + t];
            } else {
                na = alpha[t];
            }
        }
        __syncthreads();
        if (t < LBL) alpha[t] = na;
        __syncthreads();
    }
    if (t == 0) {
        float mx = -1e30f;
#pragma unroll
        for (int j = 0; j < LBL; ++j) mx = fmaxf(mx, alpha[j] + ep[j]);
        float sm = 0.f;
#pragma unroll
        for (int j = 0; j < LBL; ++j) sm += expf(alpha[j] + ep[j] - mx);
        partial[b] = (mx + logf(sm)) - num;
    }
}

__global__ void finalize_k(const float* __restrict__ partial, float* __restrict__ out) {
    float s = 0.f;
    for (int i = 0; i < BATCH; ++i) s += partial[i];
    out[0] = s;
}

__global__ void sentinel_k(float* out) { out[0] = -12345.0f; }

extern "C" void kernel_launch(void* const* d_in, const int* in_sizes, int n_in,
                              void* d_out, int out_size, void* d_ws, size_t ws_size,
                              hipStream_t stream) {
    (void)in_sizes; (void)n_in; (void)out_size;
    const int* token_ids  = (const int*)d_in[0];
    const int* token_type = (const int*)d_in[1];
    const int* amask      = (const int*)d_in[2];
    const int* y          = (const int*)d_in[3];
    const float* wemb = (const float*)d_in[4];
    const float* pemb = (const float*)d_in[5];
    const float* temb = (const float*)d_in[6];
    const float* eg   = (const float*)d_in[7];
    const float* eb   = (const float*)d_in[8];
    const float* Wq = (const float*)d_in[9];
    const float* bq = (const float*)d_in[10];
    const float* Wk = (const float*)d_in[11];
    const float* bk = (const float*)d_in[12];
    const float* Wv = (const float*)d_in[13];
    const float* bv = (const float*)d_in[14];
    const float* Wo = (const float*)d_in[15];
    const float* bo = (const float*)d_in[16];
    const float* ln1g = (const float*)d_in[17];
    const float* ln1b = (const float*)d_in[18];
    const float* W1 = (const float*)d_in[19];
    const float* b1 = (const float*)d_in[20];
    const float* W2 = (const float*)d_in[21];
    const float* b2 = (const float*)d_in[22];
    const float* ln2g = (const float*)d_in[23];
    const float* ln2b = (const float*)d_in[24];
    const float* fcw = (const float*)d_in[25];
    const float* crf_s = (const float*)d_in[26];
    const float* crf_e = (const float*)d_in[27];
    const float* crf_t = (const float*)d_in[28];

    if (ws_size < WS_FLOATS * sizeof(float)) {
        sentinel_k<<<1, 1, 0, stream>>>((float*)d_out);
        return;
    }

    float* ws = (float*)d_ws;
    float*   hbuf = ws + H_OFF;
    float*   tmp  = ws + TMP_OFF;
    ushortT* hb   = (ushortT*)(ws + HB_OFF);
    ushortT* qb   = (ushortT*)(ws + QB_OFF);
    ushortT* kb   = (ushortT*)(ws + KB_OFF);
    ushortT* vt   = (ushortT*)(ws + VT_OFF);
    ushortT* big  = (ushortT*)(ws + BIG_OFF);
    ushortT* wtq  = (ushortT*)(ws + WTQ_OFF);
    ushortT* wtk  = (ushortT*)(ws + WTK_OFF);
    ushortT* wtv  = (ushortT*)(ws + WTV_OFF);
    ushortT* wto  = (ushortT*)(ws + WTO_OFF);
    ushortT* wt1  = (ushortT*)(ws + WT1_OFF);
    ushortT* wt2  = (ushortT*)(ws + WT2_OFF);
    float*   embuf = ws + EM_OFF;
    float*   part  = ws + PART_OFF;

    embed_ln_k<<<TOKENS, 256, 0, stream>>>(token_ids, token_type, wemb, pemb, temb,
                                           eg, eb, hbuf, hb);

    constexpr long long HH = (long long)H * H;
    constexpr long long HF = (long long)H * FF;
    constexpr long long TOKH = (long long)S * H;        // 196608
    constexpr long long ATT_B = (long long)NHD * S * S; // 786432
    constexpr long long ATT_H = (long long)S * S;       // 65536
    constexpr long long VT_B = (long long)NHD * DH * S; // 196608
    constexpr long long VT_H = (long long)DH * S;       // 16384

    dim3 gProj(H / 128, TOKENS / 128, 1);      // 6 x 64
    dim3 gFF1(FF / 128, TOKENS / 128, 1);      // 24 x 64
    dim3 gScores(S / 128, S / 128, BATCH * NHD);  // 2 x 2 x 384
    dim3 gPV(1, 1, BATCH * NHD);               // 256x64 tile covers all
    dim3 gT66(H / 32, H / 32, 1);              // 24 x 24
    dim3 gT1(FF / 32, H / 32, 1);              // 96 x 24 (W1: [768][3072] -> [3072][768])
    dim3 gT2(H / 32, FF / 32, 1);              // 24 x 96

    for (int l = 0; l < NLAY; ++l) {
        transpose_cast_k<<<gT66, 256, 0, stream>>>(Wq + l * HH, wtq, H, H);
        transpose_cast_k<<<gT66, 256, 0, stream>>>(Wk + l * HH, wtk, H, H);
        transpose_cast_k<<<gT66, 256, 0, stream>>>(Wv + l * HH, wtv, H, H);
        transpose_cast_k<<<gT66, 256, 0, stream>>>(Wo + l * HH, wto, H, H);
        transpose_cast_k<<<gT1, 256, 0, stream>>>(W1 + l * HF, wt1, H, FF);
        transpose_cast_k<<<gT2, 256, 0, stream>>>(W2 + l * HF, wt2, FF, H);

        // q, k projections -> bf16
        gemm_mfma<2,2,0><<<gProj, 256, 0, stream>>>(
            hb, H, 0, 0, wtq, H, 0, 0, bq + l * H, qb, H, 0, 0, H, 1);
        gemm_mfma<2,2,0><<<gProj, 256, 0, stream>>>(
            hb, H, 0, 0, wtk, H, 0, 0, bk + l * H, kb, H, 0, 0, H, 1);
        // v projection -> v^T per head
        gemm_mfma<2,2,3><<<gProj, 256, 0, stream>>>(
            hb, H, 0, 0, wtv, H, 0, 0, bv + l * H, vt, 0, 0, 0, H, 1);

        // scores = q @ k^T  (per b,h) -> bf16
        gemm_mfma<2,2,4><<<gScores, 256, 0, stream>>>(
            qb, H, TOKH, DH, kb, H, TOKH, DH, nullptr,
            big, S, ATT_B, ATT_H, DH, NHD);

        attn_softmax_bf16_k<<<BATCH * NHD * (S / 16), 256, 0, stream>>>(big, amask);

        // ctx = probs @ v  (per b,h) -> qb as [B,S,NH,DH] bf16
        gemm_mfma<4,1,4><<<gPV, 256, 0, stream>>>(
            big, S, ATT_B, ATT_H, vt, S, VT_B, VT_H, nullptr,
            qb, H, TOKH, DH, S, NHD);

        // attention output projection -> tmp f32
        gemm_mfma<2,2,2><<<gProj, 256, 0, stream>>>(
            qb, H, 0, 0, wto, H, 0, 0, bo + l * H, tmp, H, 0, 0, H, 1);

        add_ln_k<<<TOKENS, 256, 0, stream>>>(hbuf, tmp, ln1g + l * H, ln1b + l * H, hb);

        // ff1 = gelu(h @ W1 + b1) -> big bf16
        gemm_mfma<2,2,1><<<gFF1, 256, 0, stream>>>(
            hb, H, 0, 0, wt1, H, 0, 0, b1 + (long long)l * FF, big, FF, 0, 0, H, 1);

        // ff2 -> tmp f32
        gemm_mfma<2,2,2><<<gProj, 256, 0, stream>>>(
            big, FF, 0, 0, wt2, FF, 0, 0, b2 + l * H, tmp, H, 0, 0, FF, 1);

        add_ln_k<<<TOKENS, 256, 0, stream>>>(hbuf, tmp, ln2g + l * H, ln2b + l * H, hb);
    }

    logits_k<<<TOKENS, 256, 0, stream>>>(hbuf, fcw, embuf);
    crf_k<<<BATCH, 64, 0, stream>>>(embuf, y, amask, crf_s, crf_e, crf_t, part);
    finalize_k<<<1, 1, 0, stream>>>(part, (float*)d_out);
}

// Round 3
// 3813.210 us; speedup vs baseline: 6.1107x; 1.1113x over previous
//
#include <hip/hip_runtime.h>
#include <math.h>

typedef unsigned short ushortT;
typedef __attribute__((ext_vector_type(4))) float f32x4;
typedef __attribute__((ext_vector_type(4))) unsigned int u32x4;
typedef __attribute__((ext_vector_type(4))) unsigned short u16x4;
typedef __attribute__((ext_vector_type(4))) int i32x4;

namespace {
constexpr int S = 256;
constexpr int H = 768;
constexpr int NLAY = 12;
constexpr int NHD = 12;
constexpr int FF = 3072;
constexpr int LBL = 9;
constexpr int DH = 64;
constexpr int BATCH = 32;
constexpr int TOKENS = BATCH * S;      // 8192
constexpr float SCALE = 0.125f;        // 1/sqrt(64)
constexpr int QKVN = 3 * H;            // 2304

// workspace layout (float-slot units)
constexpr size_t H_OFF   = 0;                          // h f32 [8192*768]
constexpr size_t HB_OFF  = H_OFF + (size_t)TOKENS*H;   // h bf16 (half slots)
constexpr size_t QB_OFF  = HB_OFF + (size_t)TOKENS*H/2;  // q / ctx / ff2out bf16
constexpr size_t KB_OFF  = QB_OFF + (size_t)TOKENS*H/2;  // k / attn-out bf16
constexpr size_t VT_OFF  = KB_OFF + (size_t)TOKENS*H/2;  // v^T bf16 [B*NH*DH][S]
constexpr size_t BIG_OFF = VT_OFF + (size_t)TOKENS*H/2;  // scores bf16 == ff1 bf16
constexpr size_t WTQ_OFF = BIG_OFF + (size_t)TOKENS*FF/2;  // Wq^T,Wk^T,Wv^T contiguous
constexpr size_t WTO_OFF = WTQ_OFF + 3*(size_t)H*H/2;
constexpr size_t WT1_OFF = WTO_OFF + (size_t)H*H/2;      // W1^T [3072][768]
constexpr size_t WT2_OFF = WT1_OFF + (size_t)H*FF/2;     // W2^T [768][3072]
constexpr size_t EM_OFF  = WT2_OFF + (size_t)H*FF/2;
constexpr size_t PART_OFF= EM_OFF + (size_t)TOKENS*LBL;
constexpr size_t BQKV_OFF= PART_OFF + 64;                // packed qkv bias [12][2304]
constexpr size_t WS_FLOATS = BQKV_OFF + (size_t)NLAY*QKVN;
}

__device__ __forceinline__ ushortT f2bf(float x) {
    unsigned u = __builtin_bit_cast(unsigned, x);
    u += 0x7fffu + ((u >> 16) & 1u);
    return (ushortT)(u >> 16);
}
__device__ __forceinline__ float bf2f(ushortT h) {
    unsigned u = ((unsigned)h) << 16;
    return __builtin_bit_cast(float, u);
}

__device__ inline float gelu_tanh(float x) {
    float x3 = x * x * x;
    return 0.5f * x * (1.0f + tanhf(0.7978845608028654f * (x + 0.044715f * x3)));
}

__device__ __forceinline__ void mfma_bf16(f32x4& c, const u32x4& a, const u32x4& b) {
    asm("v_mfma_f32_16x16x32_bf16 %0, %1, %2, %0" : "+v"(c) : "v"(a), "v"(b));
}

__device__ __forceinline__ void gload_lds16(const ushortT* g, ushortT* l) {
    __builtin_amdgcn_global_load_lds(
        (const __attribute__((address_space(1))) unsigned int*)g,
        (__attribute__((address_space(3))) unsigned int*)l,
        16, 0, 0);
}

// ---------------- bf16 MFMA GEMM, double-buffered 2-phase ----------------
// C[m,n] = epilogue( sum_k A[m,k] * Bt[n,k] + bias[n] )
// Tile: BM=WM*64 x BN=WN*64, BK=32, 4 waves of 64x64 each.
// MODE: 0 = bf16 out + bias, 1 = bf16 + bias + gelu, 4 = bf16 no bias,
//       5 = fused QKV routing (Cv = q base; k at +TOKENS*H; v^T at +2*TOKENS*H)
template<int WM, int WN, int MODE>
__global__ __launch_bounds__(256) void gemm_mfma(
    const ushortT* __restrict__ A, int lda, long long sAo, long long sAi,
    const ushortT* __restrict__ Bt, int ldb, long long sBo, long long sBi,
    const float* __restrict__ bias,
    void* __restrict__ Cv, int ldc, long long sCo, long long sCi,
    int K, int innerN)
{
    constexpr int BM = WM * 64, BN = WN * 64;
    __shared__ __align__(16) ushortT As[2][BM * 32];
    __shared__ __align__(16) ushortT Bs[2][BN * 32];
    const int tid = threadIdx.x;
    const int wave = tid >> 6, lane = tid & 63;
    const int ob = blockIdx.z / innerN, ib = blockIdx.z - ob * innerN;
    const int bm = blockIdx.y * BM, bn = blockIdx.x * BN;
    const ushortT* Ab = A + ob * sAo + ib * sAi + (size_t)bm * lda;
    const ushortT* Bb = Bt + ob * sBo + ib * sBi + (size_t)bn * ldb;
    const int wm = wave / WN, wn = wave - wm * WN;

    const int lrow = lane >> 2;          // 0..15 within 1KB chunk
    const int lk16 = (lane & 3) * 8;     // element offset (8 bf16 = 16B)
    const int rl = lane & 15;
    const int kg = (lane >> 4) * 8;

    f32x4 acc[4][4];
#pragma unroll
    for (int i = 0; i < 4; ++i)
#pragma unroll
        for (int j = 0; j < 4; ++j) acc[i][j] = (f32x4){0.f, 0.f, 0.f, 0.f};

    auto stage = [&](int buf, int k0) {
#pragma unroll
        for (int j = 0; j < WM; ++j) {
            int chunk = j * 4 + wave;
            gload_lds16(Ab + (size_t)(chunk * 16 + lrow) * lda + k0 + lk16,
                        &As[buf][chunk * 512]);
        }
#pragma unroll
        for (int j = 0; j < WN; ++j) {
            int chunk = j * 4 + wave;
            gload_lds16(Bb + (size_t)(chunk * 16 + lrow) * ldb + k0 + lk16,
                        &Bs[buf][chunk * 512]);
        }
    };

    stage(0, 0);
    __syncthreads();                 // buf0 landed (barrier drains vmcnt)
    const int nt = K >> 5;
    int cur = 0;
    for (int t = 0; t < nt; ++t) {
        if (t + 1 < nt) stage(cur ^ 1, (t + 1) << 5);   // prefetch overlaps MFMA
        u32x4 a[4], b[4];
#pragma unroll
        for (int mf = 0; mf < 4; ++mf)
            a[mf] = *(const u32x4*)&As[cur][(wm * 64 + mf * 16 + rl) * 32 + kg];
#pragma unroll
        for (int nf = 0; nf < 4; ++nf)
            b[nf] = *(const u32x4*)&Bs[cur][(wn * 64 + nf * 16 + rl) * 32 + kg];
#pragma unroll
        for (int mf = 0; mf < 4; ++mf)
#pragma unroll
            for (int nf = 0; nf < 4; ++nf)
                mfma_bf16(acc[mf][nf], a[mf], b[nf]);
        __syncthreads();             // drains prefetch; all waves done with cur
        cur ^= 1;
    }

    // epilogue
    ushortT* Ch = (ushortT*)Cv + ob * sCo + ib * sCi;
#pragma unroll
    for (int nf = 0; nf < 4; ++nf) {
        int gn = bn + wn * 64 + nf * 16 + rl;
        float bv = 0.f;
        if constexpr (MODE == 0 || MODE == 1 || MODE == 5) bv = bias[gn];
#pragma unroll
        for (int mf = 0; mf < 4; ++mf) {
            int gm = bm + wm * 64 + mf * 16 + ((lane >> 4) << 2);
            if constexpr (MODE == 5) {
                int region = gn / H;          // 0=q,1=k,2=v
                int col = gn - region * H;
                if (region < 2) {
                    ushortT* o = (ushortT*)Cv + (size_t)region * TOKENS * H;
#pragma unroll
                    for (int r = 0; r < 4; ++r)
                        o[(size_t)(gm + r) * H + col] = f2bf(acc[mf][nf][r] + bv);
                } else {
                    u16x4 o;
#pragma unroll
                    for (int r = 0; r < 4; ++r) o[r] = f2bf(acc[mf][nf][r] + bv);
                    int b_ = gm >> 8, s0 = gm & 255;
                    int h_ = col >> 6, dh = col & 63;
                    *(u16x4*)((ushortT*)Cv + 2 * (size_t)TOKENS * H +
                              (((size_t)(b_ * NHD + h_) * DH + dh) << 8) + s0) = o;
                }
            } else {
#pragma unroll
                for (int r = 0; r < 4; ++r) {
                    float x = acc[mf][nf][r] + bv;
                    if constexpr (MODE == 1) x = gelu_tanh(x);
                    Ch[(size_t)(gm + r) * ldc + gn] = f2bf(x);
                }
            }
        }
    }
}

// ---------------- all 6 weight transposes of one layer, one dispatch ----------------
// tiles: [0,2304) QKVO (576 each, 24x24), [2304,4608) W1 (24x96), [4608,6912) W2 (96x24)
__global__ __launch_bounds__(256) void transpose_all_k(
    const float* __restrict__ Wq, const float* __restrict__ Wk,
    const float* __restrict__ Wv, const float* __restrict__ Wo,
    const float* __restrict__ W1, const float* __restrict__ W2,
    ushortT* __restrict__ wtqkv, ushortT* __restrict__ wto,
    ushortT* __restrict__ wt1, ushortT* __restrict__ wt2)
{
    int idx = blockIdx.x;
    const float* W; ushortT* WT; int R, C, tr, tc;
    if (idx < 2304) {
        int mat = idx / 576, t = idx - mat * 576;
        tr = t / 24; tc = t - tr * 24; R = 768; C = 768;
        W = mat == 0 ? Wq : mat == 1 ? Wk : mat == 2 ? Wv : Wo;
        WT = mat < 3 ? wtqkv + (size_t)mat * 768 * 768 : wto;
    } else if (idx < 4608) {
        int t = idx - 2304; tr = t / 96; tc = t - tr * 96;
        R = 768; C = 3072; W = W1; WT = wt1;
    } else {
        int t = idx - 4608; tr = t / 24; tc = t - tr * 24;
        R = 3072; C = 768; W = W2; WT = wt2;
    }
    int r0 = tr * 32, c0 = tc * 32;
    __shared__ float tl[32][33];
    int trd = threadIdx.x >> 3;
    int tc4 = (threadIdx.x & 7) * 4;
    const float4 v = *(const float4*)(W + (size_t)(r0 + trd) * C + c0 + tc4);
    tl[trd][tc4 + 0] = v.x; tl[trd][tc4 + 1] = v.y;
    tl[trd][tc4 + 2] = v.z; tl[trd][tc4 + 3] = v.w;
    __syncthreads();
    u16x4 o;
#pragma unroll
    for (int q = 0; q < 4; ++q) o[q] = f2bf(tl[tc4 + q][trd]);
    *(u16x4*)(WT + (size_t)(c0 + trd) * R + r0 + tc4) = o;
}

// ---------------- pack qkv biases -> [NLAY][2304] ----------------
__global__ __launch_bounds__(256) void pack_bias_k(
    const float* __restrict__ bq, const float* __restrict__ bk,
    const float* __restrict__ bv, float* __restrict__ out)
{
    int l = blockIdx.x / 3, r = blockIdx.x - (blockIdx.x / 3) * 3;
    const float* src = r == 0 ? bq : r == 1 ? bk : bv;
#pragma unroll
    for (int j = 0; j < 3; ++j) {
        int d = threadIdx.x + 256 * j;
        out[(size_t)l * QKVN + r * H + d] = src[(size_t)l * H + d];
    }
}

// ---------------- block reduce helper ----------------
__device__ inline void blk_reduce2(float& s, float& ss, float* red) {
#pragma unroll
    for (int m = 32; m; m >>= 1) { s += __shfl_xor(s, m); ss += __shfl_xor(ss, m); }
    int w = threadIdx.x >> 6;
    if ((threadIdx.x & 63) == 0) { red[w] = s; red[4 + w] = ss; }
    __syncthreads();
    s = red[0] + red[1] + red[2] + red[3];
    ss = red[4] + red[5] + red[6] + red[7];
}

// ---------------- embeddings + LN (emit f32 + bf16) ----------------
__global__ __launch_bounds__(256) void embed_ln_k(
    const int* __restrict__ ids, const int* __restrict__ tts,
    const float* __restrict__ wemb, const float* __restrict__ pemb,
    const float* __restrict__ temb, const float* __restrict__ g,
    const float* __restrict__ bp, float* __restrict__ h, ushortT* __restrict__ hb)
{
    int tok = blockIdx.x, tid = threadIdx.x;
    int spos = tok & (S - 1);
    int id = ids[tok], tt = tts[tok];
    const float* wr = wemb + (size_t)id * H;
    const float* pr = pemb + (size_t)spos * H;
    const float* tr = temb + (size_t)tt * H;
    float x[3]; float s = 0.f, ss = 0.f;
#pragma unroll
    for (int j = 0; j < 3; ++j) {
        int d = tid + 256 * j;
        x[j] = wr[d] + pr[d] + tr[d];
        s += x[j]; ss += x[j] * x[j];
    }
    __shared__ float red[8];
    blk_reduce2(s, ss, red);
    float mu = s * (1.f / H);
    float var = ss * (1.f / H) - mu * mu;
    float rs = rsqrtf(var + 1e-12f);
#pragma unroll
    for (int j = 0; j < 3; ++j) {
        int d = tid + 256 * j;
        float y = (x[j] - mu) * rs * g[d] + bp[d];
        h[(size_t)tok * H + d] = y;
        hb[(size_t)tok * H + d] = f2bf(y);
    }
}

// ---------------- residual add (bf16 operand) + LN, in place on h ----------------
__global__ __launch_bounds__(256) void add_ln_k(
    float* __restrict__ h, const ushortT* __restrict__ add,
    const float* __restrict__ g, const float* __restrict__ bp,
    ushortT* __restrict__ hb)
{
    int tok = blockIdx.x, tid = threadIdx.x;
    float x[3]; float s = 0.f, ss = 0.f;
#pragma unroll
    for (int j = 0; j < 3; ++j) {
        int d = tid + 256 * j;
        x[j] = h[(size_t)tok * H + d] + bf2f(add[(size_t)tok * H + d]);
        s += x[j]; ss += x[j] * x[j];
    }
    __shared__ float red[8];
    blk_reduce2(s, ss, red);
    float mu = s * (1.f / H);
    float var = ss * (1.f / H) - mu * mu;
    float rs = rsqrtf(var + 1e-12f);
#pragma unroll
    for (int j = 0; j < 3; ++j) {
        int d = tid + 256 * j;
        float y = (x[j] - mu) * rs * g[d] + bp[d];
        h[(size_t)tok * H + d] = y;
        hb[(size_t)tok * H + d] = f2bf(y);
    }
}

// ---------------- scale + mask + softmax on bf16 scores (in place) ----------------
__global__ __launch_bounds__(256) void attn_softmax_bf16_k(
    ushortT* __restrict__ att, const int* __restrict__ mask)
{
    int blk = blockIdx.x, tid = threadIdx.x;
    int bh = blk >> 4;
    int r0 = (blk & 15) * 16;
    int b = bh / NHD;
    int r = tid >> 4, c0 = (tid & 15) * 16;
    ushortT* rp = att + ((size_t)bh * S + r0 + r) * S;
    const int* mrow = mask + (size_t)b * S;

    u32x4 x0 = *(const u32x4*)(rp + c0);
    u32x4 x1 = *(const u32x4*)(rp + c0 + 8);
    unsigned w[8];
    *(u32x4*)&w[0] = x0; *(u32x4*)&w[4] = x1;
    float v[16];
#pragma unroll
    for (int i = 0; i < 8; ++i) {
        v[2 * i]     = bf2f((ushortT)(w[i] & 0xffffu));
        v[2 * i + 1] = bf2f((ushortT)(w[i] >> 16));
    }
#pragma unroll
    for (int j = 0; j < 16; ++j)
        v[j] = v[j] * SCALE + (mrow[c0 + j] ? 0.f : -1e9f);
    float mx = -1e30f;
#pragma unroll
    for (int j = 0; j < 16; ++j) mx = fmaxf(mx, v[j]);
#pragma unroll
    for (int m = 8; m; m >>= 1) mx = fmaxf(mx, __shfl_xor(mx, m));
    float sum = 0.f;
#pragma unroll
    for (int j = 0; j < 16; ++j) { v[j] = expf(v[j] - mx); sum += v[j]; }
#pragma unroll
    for (int m = 8; m; m >>= 1) sum += __shfl_xor(sum, m);
    float inv = 1.f / sum;
#pragma unroll
    for (int i = 0; i < 8; ++i)
        w[i] = (unsigned)f2bf(v[2 * i] * inv) |
               ((unsigned)f2bf(v[2 * i + 1] * inv) << 16);
    *(u32x4*)(rp + c0) = *(u32x4*)&w[0];
    *(u32x4*)(rp + c0 + 8) = *(u32x4*)&w[4];
}

// ---------------- logits + log_softmax over 9 labels (f32 exact) ----------------
__global__ __launch_bounds__(256) void logits_k(
    const float* __restrict__ h, const float* __restrict__ fcw, float* __restrict__ em)
{
    int tok = blockIdx.x, tid = threadIdx.x;
    float p[LBL];
#pragma unroll
    for (int l = 0; l < LBL; ++l) p[l] = 0.f;
    const float* hr = h + (size_t)tok * H;
#pragma unroll
    for (int j = 0; j < 3; ++j) {
        int d = tid + 256 * j;
        float hv = hr[d];
        const float* fr = fcw + (size_t)d * LBL;
#pragma unroll
        for (int l = 0; l < LBL; ++l) p[l] = fmaf(hv, fr[l], p[l]);
    }
    __shared__ float ls[4][LBL];
    __shared__ float lg[LBL];
    __shared__ float lse;
#pragma unroll
    for (int l = 0; l < LBL; ++l) {
        float v = p[l];
#pragma unroll
        for (int m = 32; m; m >>= 1) v += __shfl_xor(v, m);
        if ((tid & 63) == 0) ls[tid >> 6][l] = v;
    }
    __syncthreads();
    if (tid < LBL) lg[tid] = ls[0][tid] + ls[1][tid] + ls[2][tid] + ls[3][tid];
    __syncthreads();
    if (tid == 0) {
        float mx = lg[0];
#pragma unroll
        for (int j = 1; j < LBL; ++j) mx = fmaxf(mx, lg[j]);
        float sm = 0.f;
#pragma unroll
        for (int j = 0; j < LBL; ++j) sm += expf(lg[j] - mx);
        lse = mx + logf(sm);
    }
    __syncthreads();
    if (tid < LBL) em[(size_t)tok * LBL + tid] = lg[tid] - lse;
}

// ---------------- CRF: one wave per batch elem, shuffle recursion ----------------
__global__ __launch_bounds__(64) void crf_k(
    const float* __restrict__ em, const int* __restrict__ tags,
    const int* __restrict__ mask, const float* __restrict__ sp,
    const float* __restrict__ ep, const float* __restrict__ trans,
    float* __restrict__ partial)
{
    int b = blockIdx.x, t = threadIdx.x;
    __shared__ float eml[S * LBL];     // 9216 B
    __shared__ int mkl[S];
    const float* emb = em + (size_t)b * S * LBL;
    const int* tg = tags + (size_t)b * S;
    const int* mk = mask + (size_t)b * S;

    for (int i = t * 4; i < S * LBL; i += 256)
        *(float4*)&eml[i] = *(const float4*)&emb[i];
    *(i32x4*)&mkl[t * 4] = *(const i32x4*)&mk[t * 4];

    // gold-path score (global reads, independent of staging)
    int cnt = 0; float ns = 0.f;
    for (int i = t; i < S; i += 64) {
        int m = mk[i];
        cnt += (m != 0);
        if (i >= 1 && m)
            ns += trans[tg[i - 1] * LBL + tg[i]] + emb[(size_t)i * LBL + tg[i]];
    }
#pragma unroll
    for (int m = 32; m; m >>= 1) { cnt += __shfl_xor(cnt, m); ns += __shfl_xor(ns, m); }
    float num = ns + sp[tg[0]] + emb[tg[0]] + ep[tg[cnt - 1]];

    // transition column for this lane: trc[i] = trans[i][t]
    int tt = t < LBL ? t : 0;
    float trc[LBL];
#pragma unroll
    for (int i = 0; i < LBL; ++i) trc[i] = trans[i * LBL + tt];

    __syncthreads();   // eml/mkl ready

    float alpha = (t < LBL) ? sp[t] + eml[t] : -1e30f;
    for (int step = 1; step < S; ++step) {
        float av[LBL];
        float mx = -1e30f;
#pragma unroll
        for (int i = 0; i < LBL; ++i) {
            av[i] = __shfl(alpha, i) + trc[i];
            mx = fmaxf(mx, av[i]);
        }
        float sm = 0.f;
#pragma unroll
        for (int i = 0; i < LBL; ++i) sm += expf(av[i] - mx);
        float na = mx + logf(sm) + eml[step * LBL + tt];
        alpha = (mkl[step] && t < LBL) ? na : alpha;
    }
    // final logsumexp(alpha + ep) over 9 lanes (16-lane group reduce)
    float z = (t < LBL) ? alpha + ep[t] : -1e30f;
    float mx = z;
#pragma unroll
    for (int m = 8; m; m >>= 1) mx = fmaxf(mx, __shfl_xor(mx, m));
    float sm = expf(z - mx);
#pragma unroll
    for (int m = 8; m; m >>= 1) sm += __shfl_xor(sm, m);
    if (t == 0) partial[b] = (mx + logf(sm)) - num;
}

__global__ void finalize_k(const float* __restrict__ partial, float* __restrict__ out) {
    float s = 0.f;
    for (int i = 0; i < BATCH; ++i) s += partial[i];
    out[0] = s;
}

__global__ void sentinel_k(float* out) { out[0] = -12345.0f; }

extern "C" void kernel_launch(void* const* d_in, const int* in_sizes, int n_in,
                              void* d_out, int out_size, void* d_ws, size_t ws_size,
                              hipStream_t stream) {
    (void)in_sizes; (void)n_in; (void)out_size;
    const int* token_ids  = (const int*)d_in[0];
    const int* token_type = (const int*)d_in[1];
    const int* amask      = (const int*)d_in[2];
    const int* y          = (const int*)d_in[3];
    const float* wemb = (const float*)d_in[4];
    const float* pemb = (const float*)d_in[5];
    const float* temb = (const float*)d_in[6];
    const float* eg   = (const float*)d_in[7];
    const float* eb   = (const float*)d_in[8];
    const float* Wq = (const float*)d_in[9];
    const float* bq = (const float*)d_in[10];
    const float* Wk = (const float*)d_in[11];
    const float* bk = (const float*)d_in[12];
    const float* Wv = (const float*)d_in[13];
    const float* bv = (const float*)d_in[14];
    const float* Wo = (const float*)d_in[15];
    const float* bo = (const float*)d_in[16];
    const float* ln1g = (const float*)d_in[17];
    const float* ln1b = (const float*)d_in[18];
    const float* W1 = (const float*)d_in[19];
    const float* b1 = (const float*)d_in[20];
    const float* W2 = (const float*)d_in[21];
    const float* b2 = (const float*)d_in[22];
    const float* ln2g = (const float*)d_in[23];
    const float* ln2b = (const float*)d_in[24];
    const float* fcw = (const float*)d_in[25];
    const float* crf_s = (const float*)d_in[26];
    const float* crf_e = (const float*)d_in[27];
    const float* crf_t = (const float*)d_in[28];

    if (ws_size < WS_FLOATS * sizeof(float)) {
        sentinel_k<<<1, 1, 0, stream>>>((float*)d_out);
        return;
    }

    float* ws = (float*)d_ws;
    float*   hbuf = ws + H_OFF;
    ushortT* hb   = (ushortT*)(ws + HB_OFF);
    ushortT* qb   = (ushortT*)(ws + QB_OFF);   // q base; k = qb+TOKENS*H; vt = +2*TOKENS*H
    ushortT* kb   = (ushortT*)(ws + KB_OFF);
    ushortT* vt   = (ushortT*)(ws + VT_OFF);
    ushortT* big  = (ushortT*)(ws + BIG_OFF);
    ushortT* wtq  = (ushortT*)(ws + WTQ_OFF);  // [2304][768] = Wq^T,Wk^T,Wv^T
    ushortT* wto  = (ushortT*)(ws + WTO_OFF);
    ushortT* wt1  = (ushortT*)(ws + WT1_OFF);
    ushortT* wt2  = (ushortT*)(ws + WT2_OFF);
    float*   embuf = ws + EM_OFF;
    float*   part  = ws + PART_OFF;
    float*   bqkv  = ws + BQKV_OFF;

    pack_bias_k<<<NLAY * 3, 256, 0, stream>>>(bq, bk, bv, bqkv);
    embed_ln_k<<<TOKENS, 256, 0, stream>>>(token_ids, token_type, wemb, pemb, temb,
                                           eg, eb, hbuf, hb);

    constexpr long long HH = (long long)H * H;
    constexpr long long HF = (long long)H * FF;
    constexpr long long TOKH = (long long)S * H;        // 196608
    constexpr long long ATT_B = (long long)NHD * S * S; // 786432
    constexpr long long ATT_H = (long long)S * S;       // 65536
    constexpr long long VT_B = (long long)NHD * DH * S; // 196608
    constexpr long long VT_H = (long long)DH * S;       // 16384

    dim3 gQKV(QKVN / 128, TOKENS / 128, 1);    // 18 x 64
    dim3 gProj(H / 128, TOKENS / 128, 1);      // 6 x 64
    dim3 gFF1(FF / 128, TOKENS / 128, 1);      // 24 x 64
    dim3 gScores(S / 128, S / 128, BATCH * NHD);  // 2 x 2 x 384
    dim3 gPV(1, 1, BATCH * NHD);               // 256x64 tile covers head

    for (int l = 0; l < NLAY; ++l) {
        transpose_all_k<<<6912, 256, 0, stream>>>(
            Wq + l * HH, Wk + l * HH, Wv + l * HH, Wo + l * HH,
            W1 + l * HF, W2 + l * HF, wtq, wto, wt1, wt2);

        // fused q,k,v projections (q->qb, k->kb, v->vt via routing epilogue)
        gemm_mfma<2,2,5><<<gQKV, 256, 0, stream>>>(
            hb, H, 0, 0, wtq, H, 0, 0, bqkv + (size_t)l * QKVN,
            qb, H, 0, 0, H, 1);

        // scores = q @ k^T  (per b,h) -> bf16
        gemm_mfma<2,2,4><<<gScores, 256, 0, stream>>>(
            qb, H, TOKH, DH, kb, H, TOKH, DH, nullptr,
            big, S, ATT_B, ATT_H, DH, NHD);

        attn_softmax_bf16_k<<<BATCH * NHD * (S / 16), 256, 0, stream>>>(big, amask);

        // ctx = probs @ v  (per b,h) -> qb as [B,S,NH,DH] bf16
        gemm_mfma<4,1,4><<<gPV, 256, 0, stream>>>(
            big, S, ATT_B, ATT_H, vt, S, VT_B, VT_H, nullptr,
            qb, H, TOKH, DH, S, NHD);

        // attention output projection -> kb (bf16)
        gemm_mfma<2,2,0><<<gProj, 256, 0, stream>>>(
            qb, H, 0, 0, wto, H, 0, 0, bo + l * H, kb, H, 0, 0, H, 1);

        add_ln_k<<<TOKENS, 256, 0, stream>>>(hbuf, kb, ln1g + l * H, ln1b + l * H, hb);

        // ff1 = gelu(h @ W1 + b1) -> big bf16
        gemm_mfma<2,2,1><<<gFF1, 256, 0, stream>>>(
            hb, H, 0, 0, wt1, H, 0, 0, b1 + (long long)l * FF, big, FF, 0, 0, H, 1);

        // ff2 -> qb (bf16)
        gemm_mfma<2,2,0><<<gProj, 256, 0, stream>>>(
            big, FF, 0, 0, wt2, FF, 0, 0, b2 + l * H, qb, H, 0, 0, FF, 1);

        add_ln_k<<<TOKENS, 256, 0, stream>>>(hbuf, qb, ln2g + l * H, ln2b + l * H, hb);
    }

    logits_k<<<TOKENS, 256, 0, stream>>>(hbuf, fcw, embuf);
    crf_k<<<BATCH, 64, 0, stream>>>(embuf, y, amask, crf_s, crf_e, crf_t, part);
    finalize_k<<<1, 1, 0, stream>>>(part, (float*)d_out);
}